// Round 14
// baseline (29.759 us; speedup 1.0000x reference)
//
#include <hip/hip_runtime.h>
#include <stdint.h>

// Problem constants (fixed by the reference).
#define T_TABLES 26
#define V_VOCAB  1000
#define D_DIM    128
#define B_BATCH  8192
#define L_BAG    8

#define SEG4   (D_DIM / 4)                   // 32 f32x4 per 128-float row
#define ROW4   ((T_TABLES + 1) * SEG4)       // 864 f32x4 per output row
#define NH     4                             // batch quarters per slice
#define HB     (B_BATCH / NH)                // 2048 rows per gather block
#define TS     (T_TABLES * 2)                // 52 (table, 64-dim-slice) pairs
#define GBLK   (TS * NH)                     // 208 gather blocks
#define NBLK   256                           // 1 block per CU
#define NDEN   (NBLK - GBLK)                 // 48 dense-copy blocks
#define NTHR   1024                          // 16 waves

typedef float    f32x4 __attribute__((ext_vector_type(4)));
typedef _Float16 f16x8 __attribute__((ext_vector_type(8)));

// R14 = R13 + indices staged in LDS as u16 (32 KB; V=1000 < 2^16).
// R12 ablation: phases are ADDITIVE (19.3 store + ~8 gather + ~2.5 stage =
// 29.5 measured). Suspected cause: stores and loads share the per-wave vmcnt
// FIFO -> the per-iter global idx loads force s_waitcnt that also drains
// STORES, exposing store latency every iteration. This loop now has ZERO
// vmem loads: idx comes from LDS (broadcast ds_read_b128, depth-1 pipelined),
// stores become pure fire-and-forget.
__global__ __launch_bounds__(NTHR)
void EmbCatDense_53309134078326_kernel(
    const int*   __restrict__ indices,   // [T, B, L] int32
    const float* __restrict__ to_cat,    // [B, D]
    const float* __restrict__ tables,    // [T, V, D]
    float*       __restrict__ out)       // [B, (T+1)*D]
{
    __shared__ uint4   slice[V_VOCAB * 8];   // 1000 rows x 64 fp16 = 125 KB
    __shared__ ushort  sidx[HB * L_BAG];     // 2048 rows x 8 u16   =  32 KB

    const int bid = blockIdx.x;
    const int tid = threadIdx.x;

    if (bid < GBLK) {
        // ---- gather block: table t, 64-dim slice s, batch quarter h ----
        const int h  = bid / TS;             // batch quarter
        const int ts = bid - h * TS;
        const int t  = ts >> 1;
        const int s  = ts & 1;
        const int b0 = h * HB;
        const int* ibase = indices + t * (B_BATCH * L_BAG);

        // Stage A: table slice as fp16, swizzled chunk c <- dims
        // {4c..4c+3, 32+4c..32+4c+3}.
        {
            const int r0 = tid >> 3, c = tid & 7;     // 128 rows per pass
            const float* srcA = tables + (size_t)t * (V_VOCAB * D_DIM)
                              + s * 64 + c * 4;
            #pragma unroll 4
            for (int it = 0; it < 8; ++it) {
                const int r = it * 128 + r0;
                if (r < V_VOCAB) {
                    const float* pr = srcA + (size_t)r * D_DIM;
                    const f32x4 a = *reinterpret_cast<const f32x4*>(pr);
                    const f32x4 e = *reinterpret_cast<const f32x4*>(pr + 32);
                    uint4 u;
                    u.x = __builtin_bit_cast(uint32_t,
                              __builtin_amdgcn_cvt_pkrtz(a.x, a.y));
                    u.y = __builtin_bit_cast(uint32_t,
                              __builtin_amdgcn_cvt_pkrtz(a.z, a.w));
                    u.z = __builtin_bit_cast(uint32_t,
                              __builtin_amdgcn_cvt_pkrtz(e.x, e.y));
                    u.w = __builtin_bit_cast(uint32_t,
                              __builtin_amdgcn_cvt_pkrtz(e.z, e.w));
                    slice[r * 8 + c] = u;
                }
            }
        }
        // Stage B: this quarter's 2048x8 indices as u16 (thread k: rows
        // 2k, 2k+1 -> 64 B coalesced read, 32 B LDS write).
        {
            const int4* ip = reinterpret_cast<const int4*>(
                ibase + (size_t)(b0 + 2 * tid) * L_BAG);
            const int4 q0 = ip[0], q1 = ip[1], q2 = ip[2], q3 = ip[3];
            uint4 u0, u1;
            u0.x = (uint32_t)q0.x | ((uint32_t)q0.y << 16);
            u0.y = (uint32_t)q0.z | ((uint32_t)q0.w << 16);
            u0.z = (uint32_t)q1.x | ((uint32_t)q1.y << 16);
            u0.w = (uint32_t)q1.z | ((uint32_t)q1.w << 16);
            u1.x = (uint32_t)q2.x | ((uint32_t)q2.y << 16);
            u1.y = (uint32_t)q2.z | ((uint32_t)q2.w << 16);
            u1.z = (uint32_t)q3.x | ((uint32_t)q3.y << 16);
            u1.w = (uint32_t)q3.z | ((uint32_t)q3.w << 16);
            uint4* sp = reinterpret_cast<uint4*>(sidx);
            sp[2 * tid]     = u0;
            sp[2 * tid + 1] = u1;
        }
        __syncthreads();

        const int w    = tid >> 6;           // wave 0..15
        const int lane = tid & 63;
        const int grp  = lane >> 3;          // 8 rows per wave-iter
        const int c    = lane & 7;           // 16 B chunk within slice row
        const f16x8* slc = reinterpret_cast<const f16x8*>(slice) + c;
        const uint4* sip = reinterpret_cast<const uint4*>(sidx);
        f32x4* o4 = reinterpret_cast<f32x4*>(out)
                  + (size_t)(t + 1) * SEG4 + s * 16 + c;

        // Depth-1 pipelined LDS idx read (broadcast within 8-lane group).
        int rrel = w * 8 + grp;              // row within quarter
        uint4 iu = sip[rrel];                // 16 B = 8 u16 indices

        for (int i = 0; i < HB / 128; ++i) { // 16 iters, 128 rows/block/iter
            uint4 nu = iu;
            if (i + 1 < HB / 128) nu = sip[rrel + 128];
            const int i0 = iu.x & 0xffff, i1 = iu.x >> 16;
            const int i2 = iu.y & 0xffff, i3 = iu.y >> 16;
            const int i4 = iu.z & 0xffff, i5 = iu.z >> 16;
            const int i6 = iu.w & 0xffff, i7 = iu.w >> 16;
            f16x8 acc = (f16x8)(_Float16)0;  // 4x v_pk_add_f16 per bag
            acc += slc[i0 * 8]; acc += slc[i1 * 8];
            acc += slc[i2 * 8]; acc += slc[i3 * 8];
            acc += slc[i4 * 8]; acc += slc[i5 * 8];
            acc += slc[i6 * 8]; acc += slc[i7 * 8];
            f32x4 vA, vB;                    // un-swizzle at store time
            vA.x = (float)acc[0]; vA.y = (float)acc[1];
            vA.z = (float)acc[2]; vA.w = (float)acc[3];   // dims 4c..4c+3
            vB.x = (float)acc[4]; vB.y = (float)acc[5];
            vB.z = (float)acc[6]; vB.w = (float)acc[7];   // dims 32+4c..+3
            const size_t row = (size_t)(b0 + rrel);
            o4[row * ROW4]     = vA;         // 8 lanes x 16 B dense 128 B
            o4[row * ROW4 + 8] = vB;
            iu = nu; rrel += 128;
        }
    } else {
        // ---- dense to_cat copy: 48 blocks, grid-stride ----
        const int db = bid - GBLK;
        const f32x4* c4 = reinterpret_cast<const f32x4*>(to_cat);
        f32x4* o4 = reinterpret_cast<f32x4*>(out);
        for (int x = db * NTHR + tid; x < B_BATCH * SEG4; x += NDEN * NTHR) {
            const int r  = x >> 5;           // x / SEG4
            const int cc = x & 31;
            const f32x4 v = __builtin_nontemporal_load(&c4[x]);
            o4[(size_t)r * ROW4 + cc] = v;
        }
    }
}

extern "C" void kernel_launch(void* const* d_in, const int* in_sizes, int n_in,
                              void* d_out, int out_size, void* d_ws, size_t ws_size,
                              hipStream_t stream) {
    const int*   indices = (const int*)  d_in[0];
    // d_in[1] = offsets [T, B] — encodes fixed bag length L, unused.
    const float* to_cat  = (const float*)d_in[2];
    const float* tables  = (const float*)d_in[3];
    float*       out     = (float*)      d_out;

    EmbCatDense_53309134078326_kernel<<<NBLK, NTHR, 0, stream>>>(
        indices, to_cat, tables, out);
}